// Round 3
// baseline (2386.127 us; speedup 1.0000x reference)
//
#include <hip/hip_runtime.h>
#include <cstdint>

typedef __attribute__((ext_vector_type(8))) short short8v;  // 8 bf16 (4 VGPR)
typedef __attribute__((ext_vector_type(4))) float f32x4;

#define KCODES 2048
#define CDIM 256
#define HWN 1024
#define MROWS 32768
#define MARGIN 1.0f
#define CAP (1 << 19)

__device__ __forceinline__ unsigned short f2bf(float f) {
  unsigned u = __float_as_uint(f);
  unsigned r = (u + 0x7fffu + ((u >> 16) & 1u)) >> 16;   // RNE
  return (unsigned short)r;
}

// ---------------- init: rkey = +inf keys, count = 0 -------------------------
__global__ __launch_bounds__(256) void init_kernel(unsigned long long* __restrict__ rkey,
                                                   int* __restrict__ count) {
  int gid = blockIdx.x * 256 + threadIdx.x;
  rkey[gid] = ~0ULL;
  if (gid == 0) *count = 0;
}

// ---------------- transpose: X[b,c,n] -> Xrow f32 [row][c] + Xbf bf16 -------
__global__ __launch_bounds__(256) void transpose_kernel(
    const float* __restrict__ X, float* __restrict__ Xrow,
    unsigned short* __restrict__ Xbf) {
  __shared__ float t[64][65];
  int bid = blockIdx.x;
  int b = bid >> 6, rem = bid & 63;
  int c0 = (rem >> 4) * 64, n0 = (rem & 15) * 64;
  int g = threadIdx.x >> 6, lane = threadIdx.x & 63;
  const float* xb = X + ((size_t)b * CDIM) * HWN;
  #pragma unroll
  for (int i = 0; i < 16; ++i) {
    int c = g * 16 + i;
    t[c][lane] = xb[(size_t)(c0 + c) * HWN + n0 + lane];   // coalesced read
  }
  __syncthreads();
  #pragma unroll
  for (int i = 0; i < 16; ++i) {
    int nn = g * 16 + i;
    float v = t[lane][nn];                                 // 2-way (free)
    size_t row = (size_t)b * HWN + n0 + nn;
    Xrow[row * CDIM + c0 + lane] = v;                      // coalesced write
    Xbf [row * CDIM + c0 + lane] = f2bf(v);
  }
}

// ---------------- e2[k] = sum E[k][c]^2 (fp32 exact) + Ebf bf16 -------------
__global__ __launch_bounds__(256) void e2_kernel(const float* __restrict__ E,
                                                 float* __restrict__ e2,
                                                 unsigned short* __restrict__ Ebf) {
  int gt = blockIdx.x * 256 + threadIdx.x;
  int k = gt >> 6, lane = threadIdx.x & 63;
  const float4 v = reinterpret_cast<const float4*>(E + (size_t)k * CDIM)[lane];
  unsigned lo = (unsigned)f2bf(v.x) | ((unsigned)f2bf(v.y) << 16);
  unsigned hi = (unsigned)f2bf(v.z) | ((unsigned)f2bf(v.w) << 16);
  uint2 p; p.x = lo; p.y = hi;
  *reinterpret_cast<uint2*>(Ebf + (size_t)k * CDIM + 4 * lane) = p;
  float s = v.x*v.x + v.y*v.y + v.z*v.z + v.w*v.w;
  #pragma unroll
  for (int off = 32; off > 0; off >>= 1) s += __shfl_down(s, off);
  if (lane == 0) e2[k] = s;
}

// ---------------- MFMA approx-distance + candidate collection ---------------
// block: 4 waves, 128 rows; wave: 32 rows (2 m-tiles). N-half per block (1024
// codes) in 16 chunks of 64 codes staged in LDS (32KB, XOR-swizzled).
// Both MFMA operands use the identical lane->(row,k) addressing on row-major
// arrays, so any k-permutation inside the fragment cancels in the dot.
__global__ __launch_bounds__(256, 2) void cand_kernel(
    const unsigned short* __restrict__ Xbf,
    const unsigned short* __restrict__ Ebf,
    const float* __restrict__ e2,
    unsigned* __restrict__ list, int* __restrict__ count)
{
  __shared__ unsigned short elds[64 * 256];   // 32 KB
  const int tid = threadIdx.x;
  const int wave = tid >> 6, lane = tid & 63;
  const int l15 = lane & 15, l4 = lane >> 4;
  const int rowblk = blockIdx.x >> 1;
  const int nhalf = blockIdx.x & 1;
  const int row0 = rowblk * 128 + wave * 32;
  const int code0 = nhalf * 1024;

  // A fragments: 32 rows x 256 ch bf16 resident in registers (64 VGPR)
  short8v af[2][8];
  #pragma unroll
  for (int mt = 0; mt < 2; ++mt)
    #pragma unroll
    for (int kt = 0; kt < 8; ++kt)
      af[mt][kt] = *reinterpret_cast<const short8v*>(
          Xbf + (size_t)(row0 + mt * 16 + l15) * CDIM + kt * 32 + l4 * 8);

  // prefetch chunk 0 (8 x 16B per thread)
  float4 stg[8];
  {
    const char* src = (const char*)Ebf + (size_t)code0 * 512;
    #pragma unroll
    for (int j = 0; j < 8; ++j)
      stg[j] = *reinterpret_cast<const float4*>(src + j * 4096 + tid * 16);
  }

  float runmin[2][4];
  #pragma unroll
  for (int mt = 0; mt < 2; ++mt)
    #pragma unroll
    for (int r = 0; r < 4; ++r) runmin[mt][r] = 3.4e38f;

  for (int chunk = 0; chunk < 16; ++chunk) {
    __syncthreads();   // previous chunk's LDS reads done
    #pragma unroll
    for (int j = 0; j < 8; ++j) {
      int L = j * 4096 + tid * 16;
      int r = L >> 9, o = L & 511;
      *reinterpret_cast<float4*>((char*)elds + r * 512 + (o ^ ((r & 7) << 4))) = stg[j];
    }
    __syncthreads();
    if (chunk < 15) {   // prefetch next chunk under the MFMAs
      const char* src = (const char*)Ebf + (size_t)(code0 + (chunk + 1) * 64) * 512;
      #pragma unroll
      for (int j = 0; j < 8; ++j)
        stg[j] = *reinterpret_cast<const float4*>(src + j * 4096 + tid * 16);
    }

    f32x4 s0[4], s1[4];
    #pragma unroll
    for (int nsub = 0; nsub < 4; ++nsub) {
      f32x4 a0 = {0.f, 0.f, 0.f, 0.f}, a1 = {0.f, 0.f, 0.f, 0.f};
      const int rn = nsub * 16 + l15;
      const char* lb = (const char*)elds + rn * 512;
      const int sw = (rn & 7) << 4;
      #pragma unroll
      for (int kt = 0; kt < 8; ++kt) {
        short8v bf = *reinterpret_cast<const short8v*>(lb + ((kt * 64 + l4 * 16) ^ sw));
        a0 = __builtin_amdgcn_mfma_f32_16x16x32_bf16(af[0][kt], bf, a0, 0, 0, 0);
        a1 = __builtin_amdgcn_mfma_f32_16x16x32_bf16(af[1][kt], bf, a1, 0, 0, 0);
      }
      const float e2v = e2[code0 + chunk * 64 + nsub * 16 + l15];
      #pragma unroll
      for (int r = 0; r < 4; ++r) {
        s0[nsub][r] = fmaf(-2.f, a0[r], e2v);
        s1[nsub][r] = fmaf(-2.f, a1[r], e2v);
      }
    }

    // chunk row-min per (mt, reg), then sync across the 16-lane code group
    float cm[2][4];
    #pragma unroll
    for (int r = 0; r < 4; ++r) {
      cm[0][r] = fminf(fminf(s0[0][r], s0[1][r]), fminf(s0[2][r], s0[3][r]));
      cm[1][r] = fminf(fminf(s1[0][r], s1[1][r]), fminf(s1[2][r], s1[3][r]));
    }
    #pragma unroll
    for (int off = 1; off < 16; off <<= 1)
      #pragma unroll
      for (int mt = 0; mt < 2; ++mt)
        #pragma unroll
        for (int r = 0; r < 4; ++r)
          cm[mt][r] = fminf(cm[mt][r], __shfl_xor(cm[mt][r], off));

    float thr[2][4];
    #pragma unroll
    for (int mt = 0; mt < 2; ++mt)
      #pragma unroll
      for (int r = 0; r < 4; ++r) {
        thr[mt][r] = fminf(runmin[mt][r], cm[mt][r]) + MARGIN;
        runmin[mt][r] = fminf(runmin[mt][r], cm[mt][r]);
      }

    // rare inserts: superset of {codes within MARGIN of final row min}
    #pragma unroll
    for (int nsub = 0; nsub < 4; ++nsub) {
      const int code = code0 + chunk * 64 + nsub * 16 + l15;
      #pragma unroll
      for (int r = 0; r < 4; ++r) {
        if (s0[nsub][r] <= thr[0][r]) {
          int row = row0 + 4 * l4 + r;
          int pos = atomicAdd(count, 1);
          if (pos < CAP) list[pos] = ((unsigned)row << 11) | (unsigned)code;
        }
        if (s1[nsub][r] <= thr[1][r]) {
          int row = row0 + 16 + 4 * l4 + r;
          int pos = atomicAdd(count, 1);
          if (pos < CAP) list[pos] = ((unsigned)row << 11) | (unsigned)code;
        }
      }
    }
  }
}

// ---------------- exact fp32 refine of candidates ---------------------------
__global__ __launch_bounds__(256) void refine_kernel(
    const float* __restrict__ Xrow, const float* __restrict__ E,
    const float* __restrict__ e2, const unsigned* __restrict__ list,
    const int* __restrict__ count, unsigned long long* __restrict__ rkey)
{
  const int lane = threadIdx.x & 63;
  const int wid = (blockIdx.x * 256 + threadIdx.x) >> 6;
  int cnt = *count; if (cnt > CAP) cnt = CAP;
  for (int i = wid; i < cnt; i += 4096) {
    unsigned p = list[i];
    int row = p >> 11, k = p & 2047;
    const float4 xv = reinterpret_cast<const float4*>(Xrow + (size_t)row * CDIM)[lane];
    const float4 ev = reinterpret_cast<const float4*>(E + (size_t)k * CDIM)[lane];
    float d = fmaf(xv.x, ev.x, fmaf(xv.y, ev.y, fmaf(xv.z, ev.z, xv.w * ev.w)));
    #pragma unroll
    for (int off = 32; off > 0; off >>= 1) d += __shfl_xor(d, off);
    if (lane == 0) {
      float s = fmaf(-2.f, d, e2[k]);
      unsigned u = __float_as_uint(s);
      u = (u & 0x80000000u) ? ~u : (u | 0x80000000u);   // monotone encode
      unsigned long long key = ((unsigned long long)u << 32) | (unsigned)k;
      atomicMin(&rkey[row], key);   // order-independent -> deterministic
    }
  }
}

// ---------------- extract argmin indices ------------------------------------
__global__ __launch_bounds__(256) void extract_kernel(
    const unsigned long long* __restrict__ rkey, int* __restrict__ idx) {
  int gid = blockIdx.x * 256 + threadIdx.x;
  idx[gid] = (int)(rkey[gid] & 2047ULL);
}

// ---------------- gather codebook rows + MSE partials -----------------------
__global__ __launch_bounds__(256) void out_kernel(
    const float* __restrict__ X, const float* __restrict__ E,
    const int* __restrict__ idx, float* __restrict__ out,
    float* __restrict__ partial)
{
  __shared__ float warpsum[4];
  size_t t = (size_t)blockIdx.x * 256 + threadIdx.x;
  size_t base = t * 8;
  float lsum = 0.f;
  #pragma unroll
  for (int g = 0; g < 2; ++g) {
    size_t e0 = base + (size_t)g * 4;
    int b = (int)(e0 >> 18);
    int c = (int)((e0 >> 10) & 255);
    int n = (int)(e0 & 1023);
    const int4 iv = *reinterpret_cast<const int4*>(idx + b * HWN + n);
    float4 q;
    q.x = E[(size_t)iv.x * CDIM + c];
    q.y = E[(size_t)iv.y * CDIM + c];
    q.z = E[(size_t)iv.z * CDIM + c];
    q.w = E[(size_t)iv.w * CDIM + c];
    const float4 xv = *reinterpret_cast<const float4*>(X + e0);
    *reinterpret_cast<float4*>(out + e0) = q;
    float dx = xv.x - q.x, dy = xv.y - q.y, dz = xv.z - q.z, dw = xv.w - q.w;
    lsum += dx*dx + dy*dy + dz*dz + dw*dw;
  }
  #pragma unroll
  for (int off = 32; off > 0; off >>= 1) lsum += __shfl_down(lsum, off);
  int lane = threadIdx.x & 63, wv = threadIdx.x >> 6;
  if (lane == 0) warpsum[wv] = lsum;
  __syncthreads();
  if (threadIdx.x == 0)
    partial[blockIdx.x] = warpsum[0] + warpsum[1] + warpsum[2] + warpsum[3];
}

// ---------------- deterministic final loss reduce ---------------------------
__global__ __launch_bounds__(256) void loss_kernel(const float* __restrict__ partial,
                                                   float* __restrict__ out_loss) {
  __shared__ double sd[256];
  double s = 0.0;
  for (int i = threadIdx.x; i < 4096; i += 256) s += (double)partial[i];
  sd[threadIdx.x] = s;
  __syncthreads();
  if (threadIdx.x == 0) {
    double tot = 0.0;
    for (int i = 0; i < 256; ++i) tot += sd[i];
    out_loss[0] = (float)(tot / 8388608.0);
  }
}

extern "C" void kernel_launch(void* const* d_in, const int* in_sizes, int n_in,
                              void* d_out, int out_size, void* d_ws, size_t ws_size,
                              hipStream_t stream) {
  const float* X = (const float*)d_in[0];   // [32,256,32,32] fp32
  const float* E = (const float*)d_in[1];   // [2048,256] fp32
  float* out = (float*)d_out;               // 8388608 quantized + 1 loss
  char* ws = (char*)d_ws;

  float*              e2    = (float*)(ws + 0);                 // 8 KB
  unsigned short*     Ebf   = (unsigned short*)(ws + 8192);     // 1 MB
  unsigned short*     Xbf   = (unsigned short*)(ws + 1056768);  // 16 MB
  unsigned long long* rkey  = (unsigned long long*)(ws + 17833984); // 256 KB
  int*                count = (int*)(ws + 18096128);            // 256 B
  int*                idx   = (int*)(ws + 18096384);            // 128 KB
  unsigned*           list  = (unsigned*)(ws + 18227456);       // 2 MB
  float*              partial = (float*)(ws + 20324608);        // 16 KB
  float* Xrow = out;   // fp32 row-major X stashed in d_out; overwritten by out_kernel

  init_kernel     <<<128,  256, 0, stream>>>(rkey, count);
  transpose_kernel<<<2048, 256, 0, stream>>>(X, Xrow, Xbf);
  e2_kernel       <<<512,  256, 0, stream>>>(E, e2, Ebf);
  cand_kernel     <<<512,  256, 0, stream>>>(Xbf, Ebf, e2, list, count);
  refine_kernel   <<<1024, 256, 0, stream>>>(Xrow, E, e2, list, count, rkey);
  extract_kernel  <<<128,  256, 0, stream>>>(rkey, idx);
  out_kernel      <<<4096, 256, 0, stream>>>(X, E, idx, out, partial);
  loss_kernel     <<<1,    256, 0, stream>>>(partial, out + 8388608);
}

// Round 4
// 261.627 us; speedup vs baseline: 9.1203x; 9.1203x over previous
//
#include <hip/hip_runtime.h>
#include <cstdint>

typedef __attribute__((ext_vector_type(8))) short short8v;  // 8 bf16 (4 VGPR)
typedef __attribute__((ext_vector_type(4))) float f32x4;

#define KCODES 2048
#define CDIM 256
#define HWN 1024
#define MROWS 32768
#define MARGIN 1.0f
#define CAP (1 << 19)
#define LCAP 4096

__device__ __forceinline__ unsigned short f2bf(float f) {
  unsigned u = __float_as_uint(f);
  unsigned r = (u + 0x7fffu + ((u >> 16) & 1u)) >> 16;   // RNE
  return (unsigned short)r;
}

// ---------------- init: rkey = +inf keys, count = 0 -------------------------
__global__ __launch_bounds__(256) void init_kernel(unsigned long long* __restrict__ rkey,
                                                   int* __restrict__ count) {
  int gid = blockIdx.x * 256 + threadIdx.x;
  rkey[gid] = ~0ULL;
  if (gid == 0) *count = 0;
}

// ---------------- transpose: X[b,c,n] -> Xrow f32 [row][c] + Xbf bf16 -------
__global__ __launch_bounds__(256) void transpose_kernel(
    const float* __restrict__ X, float* __restrict__ Xrow,
    unsigned short* __restrict__ Xbf) {
  __shared__ float t[64][65];
  int bid = blockIdx.x;
  int b = bid >> 6, rem = bid & 63;
  int c0 = (rem >> 4) * 64, n0 = (rem & 15) * 64;
  int g = threadIdx.x >> 6, lane = threadIdx.x & 63;
  const float* xb = X + ((size_t)b * CDIM) * HWN;
  #pragma unroll
  for (int i = 0; i < 16; ++i) {
    int c = g * 16 + i;
    t[c][lane] = xb[(size_t)(c0 + c) * HWN + n0 + lane];   // coalesced read
  }
  __syncthreads();
  #pragma unroll
  for (int i = 0; i < 16; ++i) {
    int nn = g * 16 + i;
    float v = t[lane][nn];                                 // 2-way (free)
    size_t row = (size_t)b * HWN + n0 + nn;
    Xrow[row * CDIM + c0 + lane] = v;                      // coalesced write
    Xbf [row * CDIM + c0 + lane] = f2bf(v);
  }
}

// ---------------- e2[k] = sum E[k][c]^2 (fp32 exact) + Ebf bf16 -------------
__global__ __launch_bounds__(256) void e2_kernel(const float* __restrict__ E,
                                                 float* __restrict__ e2,
                                                 unsigned short* __restrict__ Ebf) {
  int gt = blockIdx.x * 256 + threadIdx.x;
  int k = gt >> 6, lane = threadIdx.x & 63;
  const float4 v = reinterpret_cast<const float4*>(E + (size_t)k * CDIM)[lane];
  unsigned lo = (unsigned)f2bf(v.x) | ((unsigned)f2bf(v.y) << 16);
  unsigned hi = (unsigned)f2bf(v.z) | ((unsigned)f2bf(v.w) << 16);
  uint2 p; p.x = lo; p.y = hi;
  *reinterpret_cast<uint2*>(Ebf + (size_t)k * CDIM + 4 * lane) = p;
  float s = v.x*v.x + v.y*v.y + v.z*v.z + v.w*v.w;
  #pragma unroll
  for (int off = 32; off > 0; off >>= 1) s += __shfl_down(s, off);
  if (lane == 0) e2[k] = s;
}

// ---------------- MFMA approx-distance + candidate collection ---------------
// block: 4 waves, 128 rows; wave: 32 rows (2 m-tiles). N-half per block (1024
// codes) in 16 chunks of 64 codes staged in LDS (32KB, XOR-swizzled).
// Candidate inserts go to an LDS buffer with an LDS counter; ONE global
// atomicAdd per block publishes them (fixes the round-3 single-address
// global-atomic serialization). LDS overflow -> rare per-lane global path.
__global__ __launch_bounds__(256, 2) void cand_kernel(
    const unsigned short* __restrict__ Xbf,
    const unsigned short* __restrict__ Ebf,
    const float* __restrict__ e2,
    unsigned* __restrict__ list, int* __restrict__ count)
{
  __shared__ unsigned short elds[64 * 256];   // 32 KB
  __shared__ unsigned cbuf[LCAP];             // 16 KB
  __shared__ int lcount;
  __shared__ int gbase;
  const int tid = threadIdx.x;
  const int wave = tid >> 6, lane = tid & 63;
  const int l15 = lane & 15, l4 = lane >> 4;
  const int rowblk = blockIdx.x >> 1;
  const int nhalf = blockIdx.x & 1;
  const int row0 = rowblk * 128 + wave * 32;
  const int code0 = nhalf * 1024;

  if (tid == 0) lcount = 0;

  // A fragments: 32 rows x 256 ch bf16 resident in registers (64 VGPR)
  short8v af[2][8];
  #pragma unroll
  for (int mt = 0; mt < 2; ++mt)
    #pragma unroll
    for (int kt = 0; kt < 8; ++kt)
      af[mt][kt] = *reinterpret_cast<const short8v*>(
          Xbf + (size_t)(row0 + mt * 16 + l15) * CDIM + kt * 32 + l4 * 8);

  // prefetch chunk 0 (8 x 16B per thread)
  float4 stg[8];
  {
    const char* src = (const char*)Ebf + (size_t)code0 * 512;
    #pragma unroll
    for (int j = 0; j < 8; ++j)
      stg[j] = *reinterpret_cast<const float4*>(src + j * 4096 + tid * 16);
  }

  float runmin[2][4];
  #pragma unroll
  for (int mt = 0; mt < 2; ++mt)
    #pragma unroll
    for (int r = 0; r < 4; ++r) runmin[mt][r] = 3.4e38f;

  for (int chunk = 0; chunk < 16; ++chunk) {
    __syncthreads();   // previous chunk's LDS reads done (also covers lcount=0)
    #pragma unroll
    for (int j = 0; j < 8; ++j) {
      int L = j * 4096 + tid * 16;
      int r = L >> 9, o = L & 511;
      *reinterpret_cast<float4*>((char*)elds + r * 512 + (o ^ ((r & 7) << 4))) = stg[j];
    }
    __syncthreads();
    if (chunk < 15) {   // prefetch next chunk under the MFMAs
      const char* src = (const char*)Ebf + (size_t)(code0 + (chunk + 1) * 64) * 512;
      #pragma unroll
      for (int j = 0; j < 8; ++j)
        stg[j] = *reinterpret_cast<const float4*>(src + j * 4096 + tid * 16);
    }

    f32x4 s0[4], s1[4];
    #pragma unroll
    for (int nsub = 0; nsub < 4; ++nsub) {
      f32x4 a0 = {0.f, 0.f, 0.f, 0.f}, a1 = {0.f, 0.f, 0.f, 0.f};
      const int rn = nsub * 16 + l15;
      const char* lb = (const char*)elds + rn * 512;
      const int sw = (rn & 7) << 4;
      #pragma unroll
      for (int kt = 0; kt < 8; ++kt) {
        short8v bf = *reinterpret_cast<const short8v*>(lb + ((kt * 64 + l4 * 16) ^ sw));
        a0 = __builtin_amdgcn_mfma_f32_16x16x32_bf16(af[0][kt], bf, a0, 0, 0, 0);
        a1 = __builtin_amdgcn_mfma_f32_16x16x32_bf16(af[1][kt], bf, a1, 0, 0, 0);
      }
      const float e2v = e2[code0 + chunk * 64 + nsub * 16 + l15];
      #pragma unroll
      for (int r = 0; r < 4; ++r) {
        s0[nsub][r] = fmaf(-2.f, a0[r], e2v);
        s1[nsub][r] = fmaf(-2.f, a1[r], e2v);
      }
    }

    // chunk row-min per (mt, reg), then sync across the 16-lane code group
    float cm[2][4];
    #pragma unroll
    for (int r = 0; r < 4; ++r) {
      cm[0][r] = fminf(fminf(s0[0][r], s0[1][r]), fminf(s0[2][r], s0[3][r]));
      cm[1][r] = fminf(fminf(s1[0][r], s1[1][r]), fminf(s1[2][r], s1[3][r]));
    }
    #pragma unroll
    for (int off = 1; off < 16; off <<= 1)
      #pragma unroll
      for (int mt = 0; mt < 2; ++mt)
        #pragma unroll
        for (int r = 0; r < 4; ++r)
          cm[mt][r] = fminf(cm[mt][r], __shfl_xor(cm[mt][r], off));

    float thr[2][4];
    #pragma unroll
    for (int mt = 0; mt < 2; ++mt)
      #pragma unroll
      for (int r = 0; r < 4; ++r) {
        thr[mt][r] = fminf(runmin[mt][r], cm[mt][r]) + MARGIN;
        runmin[mt][r] = fminf(runmin[mt][r], cm[mt][r]);
      }

    // rare inserts: superset of {codes within MARGIN of final row min}
    #pragma unroll
    for (int nsub = 0; nsub < 4; ++nsub) {
      const int code = code0 + chunk * 64 + nsub * 16 + l15;
      #pragma unroll
      for (int r = 0; r < 4; ++r) {
        if (s0[nsub][r] <= thr[0][r]) {
          unsigned entry = ((unsigned)(row0 + 4 * l4 + r) << 11) | (unsigned)code;
          int pos = atomicAdd(&lcount, 1);
          if (pos < LCAP) cbuf[pos] = entry;
          else { int gp = atomicAdd(count, 1); if (gp < CAP) list[gp] = entry; }
        }
        if (s1[nsub][r] <= thr[1][r]) {
          unsigned entry = ((unsigned)(row0 + 16 + 4 * l4 + r) << 11) | (unsigned)code;
          int pos = atomicAdd(&lcount, 1);
          if (pos < LCAP) cbuf[pos] = entry;
          else { int gp = atomicAdd(count, 1); if (gp < CAP) list[gp] = entry; }
        }
      }
    }
  }

  // ---- publish the block's candidate list: ONE global atomic per block ----
  __syncthreads();
  int lc = lcount; if (lc > LCAP) lc = LCAP;
  if (tid == 0) gbase = atomicAdd(count, lc);
  __syncthreads();
  int gb = gbase;
  for (int i = tid; i < lc; i += 256) {
    int gp = gb + i;
    if (gp < CAP) list[gp] = cbuf[i];
  }
}

// ---------------- exact fp32 refine of candidates ---------------------------
__global__ __launch_bounds__(256) void refine_kernel(
    const float* __restrict__ Xrow, const float* __restrict__ E,
    const float* __restrict__ e2, const unsigned* __restrict__ list,
    const int* __restrict__ count, unsigned long long* __restrict__ rkey)
{
  const int lane = threadIdx.x & 63;
  const int wid = (blockIdx.x * 256 + threadIdx.x) >> 6;
  int cnt = *count; if (cnt > CAP) cnt = CAP;
  for (int i = wid; i < cnt; i += 4096) {
    unsigned p = list[i];
    int row = p >> 11, k = p & 2047;
    const float4 xv = reinterpret_cast<const float4*>(Xrow + (size_t)row * CDIM)[lane];
    const float4 ev = reinterpret_cast<const float4*>(E + (size_t)k * CDIM)[lane];
    float d = fmaf(xv.x, ev.x, fmaf(xv.y, ev.y, fmaf(xv.z, ev.z, xv.w * ev.w)));
    #pragma unroll
    for (int off = 32; off > 0; off >>= 1) d += __shfl_xor(d, off);
    if (lane == 0) {
      float s = fmaf(-2.f, d, e2[k]);
      unsigned u = __float_as_uint(s);
      u = (u & 0x80000000u) ? ~u : (u | 0x80000000u);   // monotone encode
      unsigned long long key = ((unsigned long long)u << 32) | (unsigned)k;
      atomicMin(&rkey[row], key);   // order-independent -> deterministic
    }
  }
}

// ---------------- extract argmin indices ------------------------------------
__global__ __launch_bounds__(256) void extract_kernel(
    const unsigned long long* __restrict__ rkey, int* __restrict__ idx) {
  int gid = blockIdx.x * 256 + threadIdx.x;
  idx[gid] = (int)(rkey[gid] & 2047ULL);
}

// ---------------- gather codebook rows + MSE partials -----------------------
__global__ __launch_bounds__(256) void out_kernel(
    const float* __restrict__ X, const float* __restrict__ E,
    const int* __restrict__ idx, float* __restrict__ out,
    float* __restrict__ partial)
{
  __shared__ float warpsum[4];
  size_t t = (size_t)blockIdx.x * 256 + threadIdx.x;
  size_t base = t * 8;
  float lsum = 0.f;
  #pragma unroll
  for (int g = 0; g < 2; ++g) {
    size_t e0 = base + (size_t)g * 4;
    int b = (int)(e0 >> 18);
    int c = (int)((e0 >> 10) & 255);
    int n = (int)(e0 & 1023);
    const int4 iv = *reinterpret_cast<const int4*>(idx + b * HWN + n);
    float4 q;
    q.x = E[(size_t)iv.x * CDIM + c];
    q.y = E[(size_t)iv.y * CDIM + c];
    q.z = E[(size_t)iv.z * CDIM + c];
    q.w = E[(size_t)iv.w * CDIM + c];
    const float4 xv = *reinterpret_cast<const float4*>(X + e0);
    *reinterpret_cast<float4*>(out + e0) = q;
    float dx = xv.x - q.x, dy = xv.y - q.y, dz = xv.z - q.z, dw = xv.w - q.w;
    lsum += dx*dx + dy*dy + dz*dz + dw*dw;
  }
  #pragma unroll
  for (int off = 32; off > 0; off >>= 1) lsum += __shfl_down(lsum, off);
  int lane = threadIdx.x & 63, wv = threadIdx.x >> 6;
  if (lane == 0) warpsum[wv] = lsum;
  __syncthreads();
  if (threadIdx.x == 0)
    partial[blockIdx.x] = warpsum[0] + warpsum[1] + warpsum[2] + warpsum[3];
}

// ---------------- deterministic final loss reduce ---------------------------
__global__ __launch_bounds__(256) void loss_kernel(const float* __restrict__ partial,
                                                   float* __restrict__ out_loss) {
  __shared__ double sd[256];
  double s = 0.0;
  for (int i = threadIdx.x; i < 4096; i += 256) s += (double)partial[i];
  sd[threadIdx.x] = s;
  __syncthreads();
  if (threadIdx.x == 0) {
    double tot = 0.0;
    for (int i = 0; i < 256; ++i) tot += sd[i];
    out_loss[0] = (float)(tot / 8388608.0);
  }
}

extern "C" void kernel_launch(void* const* d_in, const int* in_sizes, int n_in,
                              void* d_out, int out_size, void* d_ws, size_t ws_size,
                              hipStream_t stream) {
  const float* X = (const float*)d_in[0];   // [32,256,32,32] fp32
  const float* E = (const float*)d_in[1];   // [2048,256] fp32
  float* out = (float*)d_out;               // 8388608 quantized + 1 loss
  char* ws = (char*)d_ws;

  float*              e2    = (float*)(ws + 0);                 // 8 KB
  unsigned short*     Ebf   = (unsigned short*)(ws + 8192);     // 1 MB
  unsigned short*     Xbf   = (unsigned short*)(ws + 1056768);  // 16 MB
  unsigned long long* rkey  = (unsigned long long*)(ws + 17833984); // 256 KB
  int*                count = (int*)(ws + 18096128);            // 256 B
  int*                idx   = (int*)(ws + 18096384);            // 128 KB
  unsigned*           list  = (unsigned*)(ws + 18227456);       // 2 MB
  float*              partial = (float*)(ws + 20324608);        // 16 KB
  float* Xrow = out;   // fp32 row-major X stashed in d_out; overwritten by out_kernel

  init_kernel     <<<128,  256, 0, stream>>>(rkey, count);
  transpose_kernel<<<2048, 256, 0, stream>>>(X, Xrow, Xbf);
  e2_kernel       <<<512,  256, 0, stream>>>(E, e2, Ebf);
  cand_kernel     <<<512,  256, 0, stream>>>(Xbf, Ebf, e2, list, count);
  refine_kernel   <<<1024, 256, 0, stream>>>(Xrow, E, e2, list, count, rkey);
  extract_kernel  <<<128,  256, 0, stream>>>(rkey, idx);
  out_kernel      <<<4096, 256, 0, stream>>>(X, E, idx, out, partial);
  loss_kernel     <<<1,    256, 0, stream>>>(partial, out + 8388608);
}